// Round 3
// baseline (244.885 us; speedup 1.0000x reference)
//
#include <hip/hip_runtime.h>
#include <hip/hip_bf16.h>

#define B_DIM 8192
#define D_DIM 256
#define GRID_GEMM 4096

constexpr float INV_T = 14.285714285714286f;   // 1/0.07; also the logsumexp shift M

typedef __bf16 bf16x8 __attribute__((ext_vector_type(8)));
typedef float  f32x4  __attribute__((ext_vector_type(4)));

#define GLOBAL_U32(p) ((const __attribute__((address_space(1))) unsigned int*)(p))
#define LDS_U32(p)    ((__attribute__((address_space(3))) unsigned int*)(p))

__device__ inline unsigned short f2bf(float f) {
    union { float f; unsigned u; } x; x.f = f;
    unsigned r = x.u + 0x7fffu + ((x.u >> 16) & 1u);  // RNE
    return (unsigned short)(r >> 16);
}

// Kernel 1: q = normalize(h+r), t = normalize(t) -> bf16 workspace.
// Block 0 additionally zeroes rowsum/diagsum/ticket.
__global__ __launch_bounds__(256) void norm_kernel(
    const float* __restrict__ h, const float* __restrict__ r,
    const float* __restrict__ t,
    unsigned short* __restrict__ qws, unsigned short* __restrict__ tws,
    float* __restrict__ rowsum, float* __restrict__ diagsum, int* __restrict__ ticket)
{
    if (blockIdx.x == 0) {
        float4* rs4 = (float4*)rowsum;
#pragma unroll
        for (int i = 0; i < 8; ++i)
            rs4[threadIdx.x * 8 + i] = make_float4(0.f, 0.f, 0.f, 0.f);
        if (threadIdx.x == 0) { *diagsum = 0.f; *ticket = 0; }
    }

    int wave = threadIdx.x >> 6;
    int lane = threadIdx.x & 63;
    int task = blockIdx.x * 4 + wave;
    bool isQ = task < B_DIM;
    int row  = isQ ? task : task - B_DIM;

    float4 v;
    if (isQ) {
        float4 a = ((const float4*)h)[row * 64 + lane];
        float4 b = ((const float4*)r)[row * 64 + lane];
        v = make_float4(a.x + b.x, a.y + b.y, a.z + b.z, a.w + b.w);
    } else {
        v = ((const float4*)t)[row * 64 + lane];
    }
    float s = v.x * v.x + v.y * v.y + v.z * v.z + v.w * v.w;
#pragma unroll
    for (int off = 32; off; off >>= 1) s += __shfl_xor(s, off, 64);
    float scale = 1.0f / fmaxf(sqrtf(s), 1e-12f);

    ushort4 o;
    o.x = f2bf(v.x * scale);
    o.y = f2bf(v.y * scale);
    o.z = f2bf(v.z * scale);
    o.w = f2bf(v.w * scale);
    ushort4* dst = (ushort4*)(isQ ? qws : tws);
    dst[row * 64 + lane] = o;
}

// Kernel 2: m97-structure GEMM + fused exp-sum/diag epilogue + ticket finalize.
// Grid 4096 = 64 row-blocks x 64 col-blocks. Block tile 128x128, K=256 in 4
// chunks of BK=64. Both tiles staged via global_load_lds(16B) with XOR chunk
// swizzle p = kc ^ (m&7): staging stays lane-contiguous in LDS (legal) and
// frag ds_read_b128s land 2-way-conflict-free. Wave = 64x64 (4x4 MFMA tiles).
// Epilogue runs ONCE per block (K fits in the accumulator).
__global__ __launch_bounds__(256) void gemm_lse_kernel(
    const unsigned char* __restrict__ qws, const unsigned char* __restrict__ tws,
    float* __restrict__ rowsum, float* __restrict__ diagsum,
    int* __restrict__ ticket, float* __restrict__ out)
{
    __shared__ __align__(16) unsigned char ldsA[128 * 128];  // 128 rows x 64k x 2B
    __shared__ __align__(16) unsigned char ldsB[128 * 128];
    __shared__ float wred[4];
    __shared__ int lastflag;

    const int tid  = threadIdx.x;
    const int lane = tid & 63;
    const int w    = tid >> 6;
    const int quad = lane >> 4;
    const int l15  = lane & 15;
    const int wm   = w >> 1;          // wave row 0..1
    const int wn   = w & 1;           // wave col 0..1

    const int rb   = blockIdx.x & 63;
    const int nc   = blockIdx.x >> 6;
    const int row0 = rb * 128;
    const int col0 = nc * 128;

    // staging: slot s = it*256+tid -> row m = s>>3, phys chunk p = s&7,
    // logical chunk kc = p ^ (m&7); global offset = m*512 + kb*128 + kc*16
    int srel[4];
#pragma unroll
    for (int it = 0; it < 4; ++it) {
        int s = it * 256 + tid;
        int m = s >> 3;
        int kc = (s & 7) ^ (m & 7);
        srel[it] = m * 512 + kc * 16;
    }
    const unsigned char* aSrc = qws + (size_t)row0 * 512;
    const unsigned char* bSrc = tws + (size_t)col0 * 512;

    f32x4 acc[4][4];
#pragma unroll
    for (int rt = 0; rt < 4; ++rt)
#pragma unroll
        for (int ct = 0; ct < 4; ++ct)
            acc[rt][ct] = f32x4{0.f, 0.f, 0.f, 0.f};

    for (int kb = 0; kb < 4; ++kb) {
        __syncthreads();   // previous chunk's frag reads done
#pragma unroll
        for (int it = 0; it < 4; ++it) {
            __builtin_amdgcn_global_load_lds(
                GLOBAL_U32(aSrc + kb * 128 + srel[it]),
                LDS_U32(ldsA + (it * 256 + tid) * 16), 16, 0, 0);
            __builtin_amdgcn_global_load_lds(
                GLOBAL_U32(bSrc + kb * 128 + srel[it]),
                LDS_U32(ldsB + (it * 256 + tid) * 16), 16, 0, 0);
        }
        __syncthreads();   // staging complete

#pragma unroll
        for (int ks = 0; ks < 2; ++ks) {
            const int sw = ((ks * 4 + quad) ^ (l15 & 7)) * 16;
            bf16x8 a[4], b[4];
#pragma unroll
            for (int rt = 0; rt < 4; ++rt)
                a[rt] = *(const bf16x8*)(ldsA + (wm * 64 + rt * 16 + l15) * 128 + sw);
#pragma unroll
            for (int ct = 0; ct < 4; ++ct)
                b[ct] = *(const bf16x8*)(ldsB + (wn * 64 + ct * 16 + l15) * 128 + sw);
#pragma unroll
            for (int rt = 0; rt < 4; ++rt)
#pragma unroll
                for (int ct = 0; ct < 4; ++ct)
                    acc[rt][ct] = __builtin_amdgcn_mfma_f32_16x16x32_bf16(
                        a[rt], b[ct], acc[rt][ct], 0, 0, 0);
        }
    }

    // ---- epilogue (once per block): exp-sum rows, grab diagonal ----
    float rowacc[4][4];
#pragma unroll
    for (int rt = 0; rt < 4; ++rt)
#pragma unroll
        for (int i = 0; i < 4; ++i) rowacc[rt][i] = 0.f;
    float diagacc = 0.f;

#pragma unroll
    for (int rt = 0; rt < 4; ++rt) {
#pragma unroll
        for (int ct = 0; ct < 4; ++ct) {
            const bool isdiag =
                (row0 + wm * 64 + rt * 16) == (col0 + wn * 64 + ct * 16);
#pragma unroll
            for (int i = 0; i < 4; ++i) {
                float d = acc[rt][ct][i];
                rowacc[rt][i] += __expf(fmaf(d, INV_T, -INV_T));
                if (isdiag && l15 == quad * 4 + i)
                    diagacc += d * INV_T;
            }
        }
    }

#pragma unroll
    for (int rt = 0; rt < 4; ++rt)
#pragma unroll
        for (int i = 0; i < 4; ++i) {
            float s = rowacc[rt][i];
            s += __shfl_xor(s, 1, 64);
            s += __shfl_xor(s, 2, 64);
            s += __shfl_xor(s, 4, 64);
            s += __shfl_xor(s, 8, 64);
            if (l15 == 0)
                atomicAdd(&rowsum[row0 + wm * 64 + rt * 16 + quad * 4 + i], s);
        }

    float dsum = diagacc;
#pragma unroll
    for (int off = 32; off; off >>= 1) dsum += __shfl_xor(dsum, off, 64);
    if (lane == 0 && dsum != 0.f) atomicAdd(diagsum, dsum);

    // ---- ticket: last block computes the loss ----
    __syncthreads();
    if (tid == 0) {
        __threadfence();
        int old = __hip_atomic_fetch_add(ticket, 1, __ATOMIC_ACQ_REL,
                                         __HIP_MEMORY_SCOPE_AGENT);
        lastflag = (old == GRID_GEMM - 1);
    }
    __syncthreads();
    if (!lastflag) return;

    float lsum = 0.f;
    for (int rr = tid; rr < B_DIM; rr += 256) {
        float rs = __hip_atomic_load(&rowsum[rr], __ATOMIC_RELAXED,
                                     __HIP_MEMORY_SCOPE_AGENT);
        lsum += __logf(rs);
    }
#pragma unroll
    for (int off = 32; off; off >>= 1) lsum += __shfl_xor(lsum, off, 64);
    if (lane == 0) wred[w] = lsum;
    __syncthreads();
    if (tid == 0) {
        float ds = __hip_atomic_load(diagsum, __ATOMIC_RELAXED,
                                     __HIP_MEMORY_SCOPE_AGENT);
        float total = wred[0] + wred[1] + wred[2] + wred[3]
                    + (float)B_DIM * INV_T   // + M per row
                    - ds;                    // - positive logits
        out[0] = total / (float)B_DIM;
    }
}

extern "C" void kernel_launch(void* const* d_in, const int* in_sizes, int n_in,
                              void* d_out, int out_size, void* d_ws, size_t ws_size,
                              hipStream_t stream)
{
    const float* h = (const float*)d_in[0];
    const float* r = (const float*)d_in[1];
    const float* t = (const float*)d_in[2];

    unsigned char* ws = (unsigned char*)d_ws;
    unsigned short* qws = (unsigned short*)ws;                        // 4 MB
    unsigned short* tws = (unsigned short*)(ws + 4u * 1024 * 1024);   // 4 MB
    float* rowsum  = (float*)(ws + 8u * 1024 * 1024);                 // 32 KB
    float* diagsum = (float*)(ws + 8u * 1024 * 1024 + 32u * 1024);
    int*   ticket  = (int*)  (ws + 8u * 1024 * 1024 + 32u * 1024 + 16);

    norm_kernel<<<4096, 256, 0, stream>>>(h, r, t, qws, tws, rowsum, diagsum, ticket);
    gemm_lse_kernel<<<GRID_GEMM, 256, 0, stream>>>(
        (const unsigned char*)qws, (const unsigned char*)tws,
        rowsum, diagsum, ticket, (float*)d_out);
}

// Round 4
// 137.741 us; speedup vs baseline: 1.7779x; 1.7779x over previous
//
#include <hip/hip_runtime.h>
#include <hip/hip_bf16.h>

#define B_DIM 8192
#define D_DIM 256
#define GRID_GEMM 512
#define NT 16

constexpr float INV_T = 14.285714285714286f;   // 1/0.07; also the logsumexp shift M

typedef __bf16 bf16x8 __attribute__((ext_vector_type(8)));
typedef float  f32x16 __attribute__((ext_vector_type(16)));

#define GLOBAL_U32(p) ((const __attribute__((address_space(1))) unsigned int*)(p))
#define LDS_U32(p)    ((__attribute__((address_space(3))) unsigned int*)(p))

__device__ inline unsigned short f2bf(float f) {
    union { float f; unsigned u; } x; x.f = f;
    unsigned r = x.u + 0x7fffu + ((x.u >> 16) & 1u);  // RNE
    return (unsigned short)(r >> 16);
}

// Kernel 1: q = normalize(h+r), t = normalize(t) -> bf16 workspace.
// Block 0 additionally zeroes rowsum/diagsum/ticket.
__global__ __launch_bounds__(256) void norm_kernel(
    const float* __restrict__ h, const float* __restrict__ r,
    const float* __restrict__ t,
    unsigned short* __restrict__ qws, unsigned short* __restrict__ tws,
    float* __restrict__ rowsum, float* __restrict__ diagsum, int* __restrict__ ticket)
{
    if (blockIdx.x == 0) {
        float4* rs4 = (float4*)rowsum;
#pragma unroll
        for (int i = 0; i < 8; ++i)
            rs4[threadIdx.x * 8 + i] = make_float4(0.f, 0.f, 0.f, 0.f);
        if (threadIdx.x == 0) { *diagsum = 0.f; *ticket = 0; }
    }

    int wave = threadIdx.x >> 6;
    int lane = threadIdx.x & 63;
    int task = blockIdx.x * 4 + wave;
    bool isQ = task < B_DIM;
    int row  = isQ ? task : task - B_DIM;

    float4 v;
    if (isQ) {
        float4 a = ((const float4*)h)[row * 64 + lane];
        float4 b = ((const float4*)r)[row * 64 + lane];
        v = make_float4(a.x + b.x, a.y + b.y, a.z + b.z, a.w + b.w);
    } else {
        v = ((const float4*)t)[row * 64 + lane];
    }
    float s = v.x * v.x + v.y * v.y + v.z * v.z + v.w * v.w;
#pragma unroll
    for (int off = 32; off; off >>= 1) s += __shfl_xor(s, off, 64);
    float scale = 1.0f / fmaxf(sqrtf(s), 1e-12f);

    ushort4 o;
    o.x = f2bf(v.x * scale);
    o.y = f2bf(v.y * scale);
    o.z = f2bf(v.z * scale);
    o.w = f2bf(v.w * scale);
    ushort4* dst = (ushort4*)(isQ ? qws : tws);
    dst[row * 64 + lane] = o;
}

// Kernel 2: A-in-registers streaming GEMM + fused exp-sum/diag + ticket finalize.
// Grid 512 = 64 row-blocks x 8 col-chunks. Block = 128 rows x 1024 cols,
// streamed as 16 x 64-col tiles with double-buffered B LDS (2 x 32 KB).
// Wave = 64 rows x 32 cols using mfma_f32_32x32x16_bf16 (1 B-read : 2 MFMA).
// A (64 rows x K=256) lives in 128 VGPRs per wave, loaded once.
// B LDS layout XOR-swizzled (chunk p = kc ^ (n&7)): global_load_lds-legal,
// conflict-free frag reads.
__global__ __launch_bounds__(256, 2) void gemm_lse_kernel(
    const unsigned char* __restrict__ qws, const unsigned char* __restrict__ tws,
    float* __restrict__ rowsum, float* __restrict__ diagsum,
    int* __restrict__ ticket, float* __restrict__ out)
{
    __shared__ __align__(16) unsigned char ldsB[2][64 * 512];
    __shared__ float wred[4];
    __shared__ int lastflag;

    const int tid  = threadIdx.x;
    const int lane = tid & 63;
    const int w    = tid >> 6;
    const int l31  = lane & 31;
    const int hi   = lane >> 5;
    const int wm   = w >> 1;           // wave row half (0..1)
    const int wn   = w & 1;            // wave col half (0..1)

    const int rb   = blockIdx.x & 63;
    const int cc   = blockIdx.x >> 6;
    const int row0 = rb * 128 + wm * 64;     // this wave's first row
    const int col0 = cc * 1024;              // block's col chunk

    // ---- A fragments in registers: rows row0..row0+63, full K=256 ----
    // 32x32x16 A layout: m = lane&31, k = ks*16 + hi*8 + j  (16B per frag)
    bf16x8 a[2][16];
    {
        const unsigned char* abase = qws + (size_t)(row0 + l31) * 512 + hi * 16;
#pragma unroll
        for (int rt = 0; rt < 2; ++rt)
#pragma unroll
            for (int ks = 0; ks < 16; ++ks)
                a[rt][ks] = *(const bf16x8*)(abase + rt * (32 * 512) + ks * 32);
    }

    // ---- staging map: slot s -> row n = s>>5, phys chunk p = s&31,
    //      logical chunk kc = p ^ (n&7); global ofs = n*512 + kc*16 ----
    int srel[8];
#pragma unroll
    for (int it = 0; it < 8; ++it) {
        int s = it * 256 + tid;
        int n = s >> 5;
        int kc = (s & 31) ^ (n & 7);
        srel[it] = n * 512 + kc * 16;
    }
    const unsigned char* bSrc = tws + (size_t)col0 * 512;

    f32x16 rowacc[2] = {};
    float diagacc = 0.f;

    // prologue: stage tile 0 into buffer 0
#pragma unroll
    for (int it = 0; it < 8; ++it)
        __builtin_amdgcn_global_load_lds(GLOBAL_U32(bSrc + srel[it]),
                                         LDS_U32(&ldsB[0][(it * 256 + tid) * 16]),
                                         16, 0, 0);

    for (int nt = 0; nt < NT; ++nt) {
        const int cur = nt & 1;
        __syncthreads();   // stage(nt) complete; all waves done reading buf[cur^1]

        if (nt + 1 < NT) {
            const unsigned char* gs = bSrc + (nt + 1) * 64 * 512;
#pragma unroll
            for (int it = 0; it < 8; ++it)
                __builtin_amdgcn_global_load_lds(
                    GLOBAL_U32(gs + srel[it]),
                    LDS_U32(&ldsB[cur ^ 1][(it * 256 + tid) * 16]), 16, 0, 0);
        }

        // ---- compute tile nt from buf[cur] ----
        const unsigned char* bbuf = ldsB[cur];
        const int nloc = wn * 32 + l31;          // local t-row (col) 0..63
        const int nsw  = nloc & 7;
        f32x16 acc0 = {}, acc1 = {};
#pragma unroll
        for (int ks = 0; ks < 16; ++ks) {
            int kc = ks * 2 + hi;
            bf16x8 b = *(const bf16x8*)(bbuf + nloc * 512 + ((kc ^ nsw) * 16));
            acc0 = __builtin_amdgcn_mfma_f32_32x32x16_bf16(a[0][ks], b, acc0, 0, 0, 0);
            acc1 = __builtin_amdgcn_mfma_f32_32x32x16_bf16(a[1][ks], b, acc1, 0, 0, 0);
        }

        // ---- epilogue (register-only): exp-sum + diagonal ----
        const int coltile = col0 + nt * 64 + wn * 32;
        const bool isd0 = (row0 == coltile);          // rt=0 tile on diagonal
        const bool isd1 = (row0 + 32 == coltile);     // rt=1 tile on diagonal
#pragma unroll
        for (int g = 0; g < 16; ++g) {
            float d0 = acc0[g], d1 = acc1[g];
            rowacc[0][g] += __expf(fmaf(d0, INV_T, -INV_T));
            rowacc[1][g] += __expf(fmaf(d1, INV_T, -INV_T));
            int rm = (g & 3) + 8 * (g >> 2) + 4 * hi;  // C/D row within 32-tile
            if (isd0 && l31 == rm) diagacc += d0 * INV_T;
            if (isd1 && l31 == rm) diagacc += d1 * INV_T;
        }
    }

    // ---- once per block: reduce across the 32 column-lanes, then atomics ----
#pragma unroll
    for (int rt = 0; rt < 2; ++rt)
#pragma unroll
        for (int g = 0; g < 16; ++g) {
            float s = rowacc[rt][g];
            s += __shfl_xor(s, 1, 64);
            s += __shfl_xor(s, 2, 64);
            s += __shfl_xor(s, 4, 64);
            s += __shfl_xor(s, 8, 64);
            s += __shfl_xor(s, 16, 64);
            if (l31 == 0) {
                int grow = row0 + rt * 32 + (g & 3) + 8 * (g >> 2) + 4 * hi;
                atomicAdd(&rowsum[grow], s);
            }
        }

    float dsum = diagacc;
#pragma unroll
    for (int off = 32; off; off >>= 1) dsum += __shfl_xor(dsum, off, 64);
    if (lane == 0 && dsum != 0.f) atomicAdd(diagsum, dsum);

    // ---- ticket: last block computes the loss ----
    __syncthreads();
    if (tid == 0) {
        __threadfence();
        int old = __hip_atomic_fetch_add(ticket, 1, __ATOMIC_ACQ_REL,
                                         __HIP_MEMORY_SCOPE_AGENT);
        lastflag = (old == GRID_GEMM - 1);
    }
    __syncthreads();
    if (!lastflag) return;

    float lsum = 0.f;
    for (int rr = tid; rr < B_DIM; rr += 256) {
        float rs = __hip_atomic_load(&rowsum[rr], __ATOMIC_RELAXED,
                                     __HIP_MEMORY_SCOPE_AGENT);
        lsum += __logf(rs);
    }
#pragma unroll
    for (int off = 32; off; off >>= 1) lsum += __shfl_xor(lsum, off, 64);
    if (lane == 0) wred[w] = lsum;
    __syncthreads();
    if (tid == 0) {
        float ds = __hip_atomic_load(diagsum, __ATOMIC_RELAXED,
                                     __HIP_MEMORY_SCOPE_AGENT);
        float total = wred[0] + wred[1] + wred[2] + wred[3]
                    + (float)B_DIM * INV_T   // + M per row
                    - ds;                    // - positive logits
        out[0] = total / (float)B_DIM;
    }
}

extern "C" void kernel_launch(void* const* d_in, const int* in_sizes, int n_in,
                              void* d_out, int out_size, void* d_ws, size_t ws_size,
                              hipStream_t stream)
{
    const float* h = (const float*)d_in[0];
    const float* r = (const float*)d_in[1];
    const float* t = (const float*)d_in[2];

    unsigned char* ws = (unsigned char*)d_ws;
    unsigned short* qws = (unsigned short*)ws;                        // 4 MB
    unsigned short* tws = (unsigned short*)(ws + 4u * 1024 * 1024);   // 4 MB
    float* rowsum  = (float*)(ws + 8u * 1024 * 1024);                 // 32 KB
    float* diagsum = (float*)(ws + 8u * 1024 * 1024 + 32u * 1024);
    int*   ticket  = (int*)  (ws + 8u * 1024 * 1024 + 32u * 1024 + 16);

    norm_kernel<<<4096, 256, 0, stream>>>(h, r, t, qws, tws, rowsum, diagsum, ticket);
    gemm_lse_kernel<<<GRID_GEMM, 256, 0, stream>>>(
        (const unsigned char*)qws, (const unsigned char*)tws,
        rowsum, diagsum, ticket, (float*)d_out);
}

// Round 5
// 132.541 us; speedup vs baseline: 1.8476x; 1.0392x over previous
//
#include <hip/hip_runtime.h>
#include <hip/hip_bf16.h>

#define B_DIM 8192
#define D_DIM 256
#define GRID_GEMM 512
#define NT 16   // 32-col tiles per block (512 cols per block)

constexpr float INV_T = 14.285714285714286f;   // 1/0.07; also the logsumexp shift M

typedef __bf16 bf16x8 __attribute__((ext_vector_type(8)));
typedef float  f32x16 __attribute__((ext_vector_type(16)));

#define GLOBAL_U32(p) ((const __attribute__((address_space(1))) unsigned int*)(p))
#define LDS_U32(p)    ((__attribute__((address_space(3))) unsigned int*)(p))

// s_waitcnt imm (gfx9): vm[3:0]=bits3:0, exp=bits6:4, lgkm=bits11:8, vm[5:4]=bits15:14
// vmcnt(8), expcnt/lgkmcnt = no-wait:
#define WAITCNT_VM8 0x0F78

__device__ inline unsigned short f2bf(float f) {
    union { float f; unsigned u; } x; x.f = f;
    unsigned r = x.u + 0x7fffu + ((x.u >> 16) & 1u);  // RNE
    return (unsigned short)(r >> 16);
}

// Kernel 1: q = normalize(h+r), t = normalize(t) -> bf16 workspace.
// Block 0 additionally zeroes rowsum/diagsum/ticket.
__global__ __launch_bounds__(256) void norm_kernel(
    const float* __restrict__ h, const float* __restrict__ r,
    const float* __restrict__ t,
    unsigned short* __restrict__ qws, unsigned short* __restrict__ tws,
    float* __restrict__ rowsum, float* __restrict__ diagsum, int* __restrict__ ticket)
{
    if (blockIdx.x == 0) {
        float4* rs4 = (float4*)rowsum;
#pragma unroll
        for (int i = 0; i < 8; ++i)
            rs4[threadIdx.x * 8 + i] = make_float4(0.f, 0.f, 0.f, 0.f);
        if (threadIdx.x == 0) { *diagsum = 0.f; *ticket = 0; }
    }

    int wave = threadIdx.x >> 6;
    int lane = threadIdx.x & 63;
    int task = blockIdx.x * 4 + wave;
    bool isQ = task < B_DIM;
    int row  = isQ ? task : task - B_DIM;

    float4 v;
    if (isQ) {
        float4 a = ((const float4*)h)[row * 64 + lane];
        float4 b = ((const float4*)r)[row * 64 + lane];
        v = make_float4(a.x + b.x, a.y + b.y, a.z + b.z, a.w + b.w);
    } else {
        v = ((const float4*)t)[row * 64 + lane];
    }
    float s = v.x * v.x + v.y * v.y + v.z * v.z + v.w * v.w;
#pragma unroll
    for (int off = 32; off; off >>= 1) s += __shfl_xor(s, off, 64);
    float scale = 1.0f / fmaxf(sqrtf(s), 1e-12f);

    ushort4 o;
    o.x = f2bf(v.x * scale);
    o.y = f2bf(v.y * scale);
    o.z = f2bf(v.z * scale);
    o.w = f2bf(v.w * scale);
    ushort4* dst = (ushort4*)(isQ ? qws : tws);
    dst[row * 64 + lane] = o;
}

// Kernel 2: A-in-registers streaming GEMM, software-pipelined with RAW
// s_barrier + s_waitcnt vmcnt(8) (no vmcnt(0) drain - the AITER technique).
// Grid 512 = 32 row-blocks x 16 col-chunks (cc is the FAST index -> each XCD
// sees 2 col-chunks = 512 KB of B, L2-resident). Block = 256 distinct rows x
// 512 cols streamed as 16 x 32-col tiles; 4 x 16 KB LDS buffers, prefetch
// distance 2. Wave = 64 rows x 32 cols, mfma_f32_32x32x16_bf16, A (64 rows x
// K=256) in 128 VGPRs. Tail keeps vmcnt(8) uniform via dummy re-stages into
// dead buffers.
__global__ __launch_bounds__(256, 2) void gemm_lse_kernel(
    const unsigned char* __restrict__ qws, const unsigned char* __restrict__ tws,
    float* __restrict__ rowsum, float* __restrict__ diagsum,
    int* __restrict__ ticket, float* __restrict__ out)
{
    __shared__ __align__(16) unsigned char ldsB[4][32 * 512];   // 64 KB
    __shared__ float wred[4];
    __shared__ int lastflag;

    const int tid  = threadIdx.x;
    const int lane = tid & 63;
    const int w    = tid >> 6;
    const int l31  = lane & 31;
    const int hi   = lane >> 5;

    const int cc   = blockIdx.x & 15;        // col chunk (fast -> XCD locality)
    const int rb   = blockIdx.x >> 4;        // row block 0..31
    const int row0 = rb * 256 + w * 64;      // this wave's 64 rows (distinct per wave)
    const int col0 = cc * 512;

    // ---- staging map: slot s -> row n = s>>5, phys chunk p = s&31,
    //      logical chunk kc = p ^ (n&7); global ofs = n*512 + kc*16 ----
    int srel[4];
#pragma unroll
    for (int it = 0; it < 4; ++it) {
        int s = it * 256 + tid;
        int n = s >> 5;
        int kc = (s & 31) ^ (n & 7);
        srel[it] = n * 512 + kc * 16;
    }

    // stage tile snt (32 cols x 512 B = 16 KB) into buffer bufi
#define STAGE(snt, bufi)                                                     \
    {                                                                        \
        const unsigned char* gs = tws + (size_t)(col0 + (snt) * 32) * 512;   \
        _Pragma("unroll")                                                    \
        for (int it = 0; it < 4; ++it)                                       \
            __builtin_amdgcn_global_load_lds(                                \
                GLOBAL_U32(gs + srel[it]),                                   \
                LDS_U32(&ldsB[bufi][(it * 256 + tid) * 16]), 16, 0, 0);      \
    }

    // prologue: tiles 0 and 1 in flight before the A-fragment loads
    STAGE(0, 0);
    STAGE(1, 1);

    // ---- A fragments in registers: rows row0..row0+63, full K=256 ----
    // 32x32x16 A layout: m = lane&31, k = ks*16 + hi*8 + j  (16B per frag)
    bf16x8 a[2][16];
    {
        const unsigned char* abase = qws + (size_t)(row0 + l31) * 512 + hi * 16;
#pragma unroll
        for (int rt = 0; rt < 2; ++rt)
#pragma unroll
            for (int ks = 0; ks < 16; ++ks)
                a[rt][ks] = *(const bf16x8*)(abase + rt * (32 * 512) + ks * 32);
    }

    f32x16 rowacc[2] = {};
    float diagacc = 0.f;
    const int nsw = l31 & 7;

    for (int nt = 0; nt < NT; ++nt) {
        // prefetch distance 2; tail: dummy re-stage of tile NT-1 into the
        // (dead) target buffer keeps the in-flight count uniform at 8.
        const int snt = (nt + 2 < NT) ? nt + 2 : NT - 1;
        STAGE(snt, (nt + 2) & 3);

        // wait for tile nt's loads only (tiles nt+1, nt+2 = 8 insts stay in
        // flight), then a raw barrier -- NO vmcnt(0) drain.
        __builtin_amdgcn_s_waitcnt(WAITCNT_VM8);
        __builtin_amdgcn_s_barrier();

        const unsigned char* bbuf = ldsB[nt & 3];
        f32x16 acc0 = {}, acc1 = {};
#pragma unroll
        for (int ks = 0; ks < 16; ++ks) {
            int kc = ks * 2 + hi;
            bf16x8 b = *(const bf16x8*)(bbuf + l31 * 512 + ((kc ^ nsw) * 16));
            acc0 = __builtin_amdgcn_mfma_f32_32x32x16_bf16(a[0][ks], b, acc0, 0, 0, 0);
            acc1 = __builtin_amdgcn_mfma_f32_32x32x16_bf16(a[1][ks], b, acc1, 0, 0, 0);
        }

        // hot epilogue: exp-sum only (diag handling hoisted below)
#pragma unroll
        for (int g = 0; g < 16; ++g) {
            rowacc[0][g] += __expf(fmaf(acc0[g], INV_T, -INV_T));
            rowacc[1][g] += __expf(fmaf(acc1[g], INV_T, -INV_T));
        }

        // diagonal tiles: wave-uniform condition, at most 2 of 16 iterations
        const int c0t = col0 + nt * 32;
        if (c0t == row0) {
#pragma unroll
            for (int g = 0; g < 16; ++g) {
                int rm = (g & 3) + 8 * (g >> 2) + 4 * hi;
                if (l31 == rm) diagacc += acc0[g] * INV_T;
            }
        }
        if (c0t == row0 + 32) {
#pragma unroll
            for (int g = 0; g < 16; ++g) {
                int rm = (g & 3) + 8 * (g >> 2) + 4 * hi;
                if (l31 == rm) diagacc += acc1[g] * INV_T;
            }
        }
    }

    // ---- once per block: reduce across the 32 column-lanes, then atomics ----
#pragma unroll
    for (int rt = 0; rt < 2; ++rt)
#pragma unroll
        for (int g = 0; g < 16; ++g) {
            float s = rowacc[rt][g];
            s += __shfl_xor(s, 1, 64);
            s += __shfl_xor(s, 2, 64);
            s += __shfl_xor(s, 4, 64);
            s += __shfl_xor(s, 8, 64);
            s += __shfl_xor(s, 16, 64);
            if (l31 == 0) {
                int grow = row0 + rt * 32 + (g & 3) + 8 * (g >> 2) + 4 * hi;
                atomicAdd(&rowsum[grow], s);
            }
        }

    float dsum = diagacc;
#pragma unroll
    for (int off = 32; off; off >>= 1) dsum += __shfl_xor(dsum, off, 64);
    if (lane == 0 && dsum != 0.f) atomicAdd(diagsum, dsum);

    // ---- ticket: last block computes the loss ----
    __syncthreads();
    if (tid == 0) {
        __threadfence();
        int old = __hip_atomic_fetch_add(ticket, 1, __ATOMIC_ACQ_REL,
                                         __HIP_MEMORY_SCOPE_AGENT);
        lastflag = (old == GRID_GEMM - 1);
    }
    __syncthreads();
    if (!lastflag) return;

    float lsum = 0.f;
    for (int rr = tid; rr < B_DIM; rr += 256) {
        float rs = __hip_atomic_load(&rowsum[rr], __ATOMIC_RELAXED,
                                     __HIP_MEMORY_SCOPE_AGENT);
        lsum += __logf(rs);
    }
#pragma unroll
    for (int off = 32; off; off >>= 1) lsum += __shfl_xor(lsum, off, 64);
    if (lane == 0) wred[w] = lsum;
    __syncthreads();
    if (tid == 0) {
        float ds = __hip_atomic_load(diagsum, __ATOMIC_RELAXED,
                                     __HIP_MEMORY_SCOPE_AGENT);
        float total = wred[0] + wred[1] + wred[2] + wred[3]
                    + (float)B_DIM * INV_T   // + M per row
                    - ds;                    // - positive logits
        out[0] = total / (float)B_DIM;
    }
}

extern "C" void kernel_launch(void* const* d_in, const int* in_sizes, int n_in,
                              void* d_out, int out_size, void* d_ws, size_t ws_size,
                              hipStream_t stream)
{
    const float* h = (const float*)d_in[0];
    const float* r = (const float*)d_in[1];
    const float* t = (const float*)d_in[2];

    unsigned char* ws = (unsigned char*)d_ws;
    unsigned short* qws = (unsigned short*)ws;                        // 4 MB
    unsigned short* tws = (unsigned short*)(ws + 4u * 1024 * 1024);   // 4 MB
    float* rowsum  = (float*)(ws + 8u * 1024 * 1024);                 // 32 KB
    float* diagsum = (float*)(ws + 8u * 1024 * 1024 + 32u * 1024);
    int*   ticket  = (int*)  (ws + 8u * 1024 * 1024 + 32u * 1024 + 16);

    norm_kernel<<<4096, 256, 0, stream>>>(h, r, t, qws, tws, rowsum, diagsum, ticket);
    gemm_lse_kernel<<<GRID_GEMM, 256, 0, stream>>>(
        (const unsigned char*)qws, (const unsigned char*)tws,
        rowsum, diagsum, ticket, (float*)d_out);
}